// Round 12
// baseline (259.452 us; speedup 1.0000x reference)
//
#include <hip/hip_runtime.h>
#include <hip/hip_bf16.h>
#include <stdint.h>

typedef unsigned short u16;
typedef __bf16 bf16x8 __attribute__((ext_vector_type(8)));
typedef float f32x4 __attribute__((ext_vector_type(4)));

#define MFMA16(a, b, c) __builtin_amdgcn_mfma_f32_16x16x32_bf16((a), (b), (c), 0, 0, 0)

#define BATCH 2
#define NSEQ 2048
#define DIMC 1024
#define NHEAD 16
#define DHEAD 64

__device__ __forceinline__ u16 f2bf(float f) {
  unsigned u = __float_as_uint(f);
  u += 0x7FFFu + ((u >> 16) & 1u);
  return (u16)(u >> 16);
}
__device__ __forceinline__ float bf2f(u16 h) {
  return __uint_as_float(((unsigned)h) << 16);
}
__device__ __forceinline__ void gload_lds16(const void* g, void* lds) {
  __builtin_amdgcn_global_load_lds((const __attribute__((address_space(1))) void*)g,
                                   (__attribute__((address_space(3))) void*)lds,
                                   16, 0, 0);
}
// counted-vmcnt waits (immediates must be literals)
#define WAIT_VM(N) asm volatile("s_waitcnt vmcnt(" #N ")" ::: "memory")
#define BARRIER() __builtin_amdgcn_s_barrier()

// ---------------------------------------------------------------------------
// fp32 -> bf16 conversion (weights)
// ---------------------------------------------------------------------------
__global__ __launch_bounds__(256) void cvt_f32_bf16(const float* __restrict__ in,
                                                    u16* __restrict__ out, int n) {
  int i = (blockIdx.x * 256 + threadIdx.x) * 4;
  if (i < n) {
    float4 v = *(const float4*)(in + i);
    ushort4 o;
    o.x = f2bf(v.x); o.y = f2bf(v.y); o.z = f2bf(v.z); o.w = f2bf(v.w);
    *(ushort4*)(out + i) = o;
  }
}

// ---------------------------------------------------------------------------
// LayerNorm: fp32 in -> bf16 out   (one block per row, 1024 cols)
// ---------------------------------------------------------------------------
__global__ __launch_bounds__(256) void ln_f32_to_bf16(const float* __restrict__ X,
                                                      const float* __restrict__ G,
                                                      const float* __restrict__ Bv,
                                                      u16* __restrict__ Y) {
  const int row = blockIdx.x;
  const int tid = threadIdx.x;
  const float4 v = *(const float4*)(X + (size_t)row * DIMC + tid * 4);
  float s = v.x + v.y + v.z + v.w;
  float q = v.x * v.x + v.y * v.y + v.z * v.z + v.w * v.w;
#pragma unroll
  for (int d = 1; d < 64; d <<= 1) {
    s += __shfl_xor(s, d, 64);
    q += __shfl_xor(q, d, 64);
  }
  __shared__ float ps[4], pq[4];
  const int w = tid >> 6, l = tid & 63;
  if (l == 0) { ps[w] = s; pq[w] = q; }
  __syncthreads();
  s = ps[0] + ps[1] + ps[2] + ps[3];
  q = pq[0] + pq[1] + pq[2] + pq[3];
  const float mean = s * (1.f / DIMC);
  const float var = q * (1.f / DIMC) - mean * mean;
  const float rs = rsqrtf(var + 1e-5f);
  const float4 g = *(const float4*)(G + tid * 4);
  const float4 bb = *(const float4*)(Bv + tid * 4);
  ushort4 o;
  o.x = f2bf((v.x - mean) * rs * g.x + bb.x);
  o.y = f2bf((v.y - mean) * rs * g.y + bb.y);
  o.z = f2bf((v.z - mean) * rs * g.z + bb.z);
  o.w = f2bf((v.w - mean) * rs * g.w + bb.w);
  *(ushort4*)(Y + (size_t)row * DIMC + tid * 4) = o;
}

// LayerNorm: bf16 in -> fp32 out
__global__ __launch_bounds__(256) void ln_bf16_to_f32(const u16* __restrict__ X,
                                                      const float* __restrict__ G,
                                                      const float* __restrict__ Bv,
                                                      float* __restrict__ Y) {
  const int row = blockIdx.x;
  const int tid = threadIdx.x;
  const ushort4 hv = *(const ushort4*)(X + (size_t)row * DIMC + tid * 4);
  float x0 = bf2f(hv.x), x1 = bf2f(hv.y), x2 = bf2f(hv.z), x3 = bf2f(hv.w);
  float s = x0 + x1 + x2 + x3;
  float q = x0 * x0 + x1 * x1 + x2 * x2 + x3 * x3;
#pragma unroll
  for (int d = 1; d < 64; d <<= 1) {
    s += __shfl_xor(s, d, 64);
    q += __shfl_xor(q, d, 64);
  }
  __shared__ float ps[4], pq[4];
  const int w = tid >> 6, l = tid & 63;
  if (l == 0) { ps[w] = s; pq[w] = q; }
  __syncthreads();
  s = ps[0] + ps[1] + ps[2] + ps[3];
  q = pq[0] + pq[1] + pq[2] + pq[3];
  const float mean = s * (1.f / DIMC);
  const float var = q * (1.f / DIMC) - mean * mean;
  const float rs = rsqrtf(var + 1e-5f);
  const float4 g = *(const float4*)(G + tid * 4);
  const float4 bb = *(const float4*)(Bv + tid * 4);
  float4 o;
  o.x = (x0 - mean) * rs * g.x + bb.x;
  o.y = (x1 - mean) * rs * g.y + bb.y;
  o.z = (x2 - mean) * rs * g.z + bb.z;
  o.w = (x3 - mean) * rs * g.w + bb.w;
  *(float4*)(Y + (size_t)row * DIMC + tid * 4) = o;
}

// ---------------------------------------------------------------------------
// GEMM  C[M,N] = A[M,K] @ Bw[N,K]^T   (bf16 in, fp32 acc)
// R5-measured-best config: 128x128 tile, BK=64, 512 threads (8 waves, 2Mx4N;
// wave = 64x32, acc 4x2). dbuf + counted-vmcnt pipeline, XOR-swizzled LDS,
// XCD-chunked block swizzle.
// MODE 0: out0[m][n] = bf16(acc * scale0)
// MODE 2: fused QKV (N=1152): col<1024 -> q*scale0 ; 1024..1087 -> k*sqs ;
//         1088..1151 -> vT[b][d][n]
// ---------------------------------------------------------------------------
template <int MODE>
__global__ __launch_bounds__(512) void gemm_bt(const u16* __restrict__ A,
                                               const u16* __restrict__ Bw,
                                               u16* __restrict__ out0,
                                               u16* __restrict__ out1,
                                               u16* __restrict__ out2,
                                               int M, int N, int K, float scale0) {
  const int tid = threadIdx.x;
  const int w = tid >> 6, l = tid & 63;
  const int wr = w >> 2, wc = w & 3;
  const int lr = l & 15, lg = l >> 4;

  // XCD-chunked bijective swizzle (nwg % 8 == 0 guaranteed by launch)
  const int nwgx = gridDim.x;
  const int nwg = nwgx * gridDim.y;
  int flat = blockIdx.x + nwgx * blockIdx.y;
  flat = (flat & 7) * (nwg >> 3) + (flat >> 3);
  const int m0 = (flat / nwgx) * 128, n0 = (flat % nwgx) * 128;

  __shared__ u16 As[2][128 * 64];   // 16 KiB each, 128B rows, XOR-swizzled
  __shared__ u16 Bs[2][128 * 64];

  f32x4 acc[4][2] = {};

  auto STAGE = [&](int buf, int kt) {
#pragma unroll
    for (int r = 0; r < 2; ++r) {
      const int c = w * 2 + r;          // chunk 0..15, 1 KiB each
      const int lo = c * 1024 + l * 16;
      const int row = lo >> 7;          // 128 B per row (64 bf16)
      const int cl = (lo & 127) ^ ((row & 7) << 4);  // inverse-swizzle source
      gload_lds16((const char*)A + ((size_t)(m0 + row) * K + kt * 64) * 2 + cl,
                  (char*)As[buf] + c * 1024);
      gload_lds16((const char*)Bw + ((size_t)(n0 + row) * K + kt * 64) * 2 + cl,
                  (char*)Bs[buf] + c * 1024);
    }
  };

  const int nk = K >> 6;
  STAGE(0, 0);
  STAGE(1, 1);          // K >= 128 always here
  int cur = 0;
  for (int kt = 0; kt < nk; ++kt) {
    if (kt + 1 < nk) { WAIT_VM(4); } else { WAIT_VM(0); }
    BARRIER();
    const char* as = (const char*)As[cur];
    const char* bs = (const char*)Bs[cur];
#pragma unroll
    for (int ks = 0; ks < 2; ++ks) {
      bf16x8 af[4], bfr[2];
#pragma unroll
      for (int mi = 0; mi < 4; ++mi) {
        const int row = wr * 64 + mi * 16 + lr;
        af[mi] = *(const bf16x8*)(as + row * 128 + ((ks * 64 + lg * 16) ^ ((row & 7) << 4)));
      }
#pragma unroll
      for (int ni = 0; ni < 2; ++ni) {
        const int row = wc * 32 + ni * 16 + lr;
        bfr[ni] = *(const bf16x8*)(bs + row * 128 + ((ks * 64 + lg * 16) ^ ((row & 7) << 4)));
      }
      __builtin_amdgcn_s_setprio(1);
#pragma unroll
      for (int mi = 0; mi < 4; ++mi)
#pragma unroll
        for (int ni = 0; ni < 2; ++ni)
          acc[mi][ni] = MFMA16(af[mi], bfr[ni], acc[mi][ni]);
      __builtin_amdgcn_s_setprio(0);
    }
    BARRIER();
    if (kt + 2 < nk) STAGE(cur, kt + 2);
    cur ^= 1;
  }

  if constexpr (MODE == 0) {
#pragma unroll
    for (int mi = 0; mi < 4; ++mi)
#pragma unroll
      for (int ni = 0; ni < 2; ++ni)
#pragma unroll
        for (int r = 0; r < 4; ++r) {
          const int row = m0 + wr * 64 + mi * 16 + lg * 4 + r;
          const int col = n0 + wc * 32 + ni * 16 + lr;
          out0[(size_t)row * N + col] = f2bf(acc[mi][ni][r] * scale0);
        }
  } else {
    const float sqs = 0.35355339059327379f;
#pragma unroll
    for (int mi = 0; mi < 4; ++mi)
#pragma unroll
      for (int ni = 0; ni < 2; ++ni)
#pragma unroll
        for (int r = 0; r < 4; ++r) {
          const int m = m0 + wr * 64 + mi * 16 + lg * 4 + r;  // b*2048+n
          const int col = n0 + wc * 32 + ni * 16 + lr;
          const float vv = acc[mi][ni][r];
          if (col < 1024) {
            out0[(size_t)m * 1024 + col] = f2bf(vv * scale0);                   // q
          } else {
            const int b = m >> 11, n = m & 2047;
            const int colk = col - 1024;
            if (colk < 64) {
              out1[(size_t)m * 64 + colk] = f2bf(vv * sqs);                     // k
            } else {
              const int d = colk - 64;
              out2[((size_t)b * 64 + d) * NSEQ + n] = f2bf(vv);                 // vT
            }
          }
        }
  }
}

// ---------------------------------------------------------------------------
// Causal flash attention (MQA: shared K/V per batch), BARRIER-FREE.
// K/V per batch = 256 KiB each -> L2-resident; no LDS staging. Each wave
// independently handles two 16-row q-chunks {c, 127-c} (exactly ~34 kv-tiles
// per wave, balanced). K / V^T MFMA fragments loaded straight from global
// (L2); only per-wave swizzled Ps LDS bounce remains (no __syncthreads).
// Branchless log2-domain online softmax, truncating bf16 P-store.
// ---------------------------------------------------------------------------
__global__ __launch_bounds__(256) void attn_causal(const u16* __restrict__ Q,
                                                   const u16* __restrict__ Kg,
                                                   const u16* __restrict__ VTg,
                                                   u16* __restrict__ O) {
  const int tid = threadIdx.x;
  const int w = tid >> 6, l = tid & 63;
  const int lr = l & 15, lg = l >> 4;
  const int gw = blockIdx.x * 4 + w;   // 0..2047
  const int bh = gw & 31;
  const int b = bh >> 4, h = bh & 15;
  const int p = gw >> 5;               // 0..63

  __shared__ u16 Ps[4][16 * 64];       // per-wave P, 128B rows, swizzled
  u16* pw = &Ps[w][0];

  const char* kb = (const char*)(Kg + (size_t)b * NSEQ * DHEAD);
  const char* vb = (const char*)(VTg + (size_t)b * DHEAD * NSEQ);

  const f32x4 ZERO4 = {0.f, 0.f, 0.f, 0.f};

#pragma unroll
  for (int half = 0; half < 2; ++half) {
    const int c = half ? (127 - p) : p;          // q-chunk 0..127 (16 rows)
    const int qrow = c * 16 + lr;
    const size_t qbase = ((size_t)(b * NSEQ + qrow)) * DIMC + h * DHEAD;
    const bf16x8 q0 = *(const bf16x8*)(Q + qbase + lg * 8);
    const bf16x8 q1 = *(const bf16x8*)(Q + qbase + 32 + lg * 8);

    float mr[4], lsum[4];
    f32x4 oa[4];
#pragma unroll
    for (int r = 0; r < 4; ++r) { mr[r] = -1e30f; lsum[r] = 0.f; }
#pragma unroll
    for (int f = 0; f < 4; ++f) oa[f] = ZERO4;

    const int dt = c >> 2;             // diagonal kv-tile index
    for (int kt = 0; kt <= dt; ++kt) {
      // S = Q @ K^T, K fragments direct from L2 (S in log2 units)
      f32x4 s[4];
      __builtin_amdgcn_s_setprio(1);
#pragma unroll
      for (int f = 0; f < 4; ++f) {
        const char* kr = kb + (size_t)(kt * 64 + f * 16 + lr) * 128;
        const bf16x8 kf0 = *(const bf16x8*)(kr + lg * 16);
        const bf16x8 kf1 = *(const bf16x8*)(kr + 64 + lg * 16);
        s[f] = MFMA16(q0, kf0, ZERO4);
        s[f] = MFMA16(q1, kf1, s[f]);
      }
      __builtin_amdgcn_s_setprio(0);

      if (kt == dt) {
#pragma unroll
        for (int f = 0; f < 4; ++f)
#pragma unroll
          for (int r = 0; r < 4; ++r)
            if (kt * 64 + f * 16 + lr > c * 16 + lg * 4 + r) s[f][r] = -1e30f;
      }

      // branchless online softmax in log2 domain (row = lg*4 + r)
#pragma unroll
      for (int r = 0; r < 4; ++r) {
        float mx = fmaxf(fmaxf(s[0][r], s[1][r]), fmaxf(s[2][r], s[3][r]));
#pragma unroll
        for (int d = 1; d < 16; d <<= 1) mx = fmaxf(mx, __shfl_xor(mx, d, 64));
        const float mnew = fmaxf(mr[r], mx);
        const float sc = exp2f(mr[r] - mnew);
        float ls = 0.f;
#pragma unroll
        for (int f = 0; f < 4; ++f) {
          const float pv = exp2f(s[f][r] - mnew);
          s[f][r] = pv;
          ls += pv;
        }
#pragma unroll
        for (int d = 1; d < 16; d <<= 1) ls += __shfl_xor(ls, d, 64);
        lsum[r] = lsum[r] * sc + ls;
        mr[r] = mnew;
#pragma unroll
        for (int f = 0; f < 4; ++f) oa[f][r] *= sc;
      }

      // P -> bf16 (truncate) -> per-wave LDS (swizzled); no barrier needed
#pragma unroll
      for (int f = 0; f < 4; ++f)
#pragma unroll
        for (int r = 0; r < 4; ++r) {
          const int row = lg * 4 + r;
          const int cbyte = (f * 16 + lr) * 2;
          *(u16*)((char*)pw + row * 128 + (cbyte ^ ((row & 7) << 4))) =
              (u16)(__float_as_uint(s[f][r]) >> 16);
        }

      // re-read P as A-fragments; V^T fragments direct from L2
      const int psw = (lr & 7) << 4;
      const bf16x8 ap0 = *(const bf16x8*)((const char*)pw + lr * 128 + ((lg * 16) ^ psw));
      const bf16x8 ap1 = *(const bf16x8*)((const char*)pw + lr * 128 + ((64 + lg * 16) ^ psw));
      __builtin_amdgcn_s_setprio(1);
#pragma unroll
      for (int f = 0; f < 4; ++f) {
        const char* vr = vb + (size_t)(f * 16 + lr) * (NSEQ * 2) + kt * 128;
        const bf16x8 vf0 = *(const bf16x8*)(vr + lg * 16);
        const bf16x8 vf1 = *(const bf16x8*)(vr + 64 + lg * 16);
        oa[f] = MFMA16(ap0, vf0, oa[f]);
        oa[f] = MFMA16(ap1, vf1, oa[f]);
      }
      __builtin_amdgcn_s_setprio(0);
    }

    float inv[4];
#pragma unroll
    for (int r = 0; r < 4; ++r) inv[r] = 1.f / lsum[r];
#pragma unroll
    for (int f = 0; f < 4; ++f)
#pragma unroll
      for (int r = 0; r < 4; ++r) {
        const int row = c * 16 + lg * 4 + r;
        const int col = h * DHEAD + f * 16 + lr;
        O[((size_t)(b * NSEQ + row)) * DIMC + col] = f2bf(oa[f][r] * inv[r]);
      }
  }
}

// ---------------------------------------------------------------------------
extern "C" void kernel_launch(void* const* d_in, const int* in_sizes, int n_in,
                              void* d_out, int out_size, void* d_ws, size_t ws_size,
                              hipStream_t stream) {
  const float* x = (const float*)d_in[0];
  const float* w_q = (const float*)d_in[1];
  const float* w_kv = (const float*)d_in[2];
  const float* w_out = (const float*)d_in[3];
  const float* ln_g = (const float*)d_in[4];
  const float* ln_b = (const float*)d_in[5];
  const float* lno_g = (const float*)d_in[6];
  const float* lno_b = (const float*)d_in[7];
  float* out = (float*)d_out;

  char* ws = (char*)d_ws;
  size_t off = 0;
  auto alloc = [&](size_t bytes) {
    char* p = ws + off;
    off += (bytes + 255) & ~(size_t)255;
    return p;
  };
  u16* xn    = (u16*)alloc((size_t)BATCH * NSEQ * DIMC * 2);   // 8 MiB
  u16* wqkv  = (u16*)alloc((size_t)1152 * DIMC * 2);           // 2.25 MiB
  u16* wob   = (u16*)alloc((size_t)DIMC * DIMC * 2);           // 2 MiB
  u16* qb    = (u16*)alloc((size_t)BATCH * NSEQ * DIMC * 2);   // 8 MiB
  u16* kb    = (u16*)alloc((size_t)BATCH * NSEQ * DHEAD * 2);  // 512 KiB
  u16* vtb   = (u16*)alloc((size_t)BATCH * DHEAD * NSEQ * 2);  // 512 KiB
  u16* ao = xn;  // attention output aliases xn (xn dead after projections)
  u16* yb = qb;  // pre-LN2 aliases q (q dead after attention)

  // scale * sqrt(scale) * log2(e)  (softmax runs in log2 domain)
  const float qscale = (float)(0.044194173824159216 * 1.4426950408889634);

  cvt_f32_bf16<<<1024, 256, 0, stream>>>(w_q, wqkv, DIMC * DIMC);
  cvt_f32_bf16<<<128, 256, 0, stream>>>(w_kv, wqkv + (size_t)DIMC * DIMC, 128 * DIMC);
  cvt_f32_bf16<<<1024, 256, 0, stream>>>(w_out, wob, DIMC * DIMC);

  ln_f32_to_bf16<<<BATCH * NSEQ, 256, 0, stream>>>(x, ln_g, ln_b, xn);

  // fused Q + KV projection: N = 1152 (grid 9x32 = 288 blocks, %8==0)
  gemm_bt<2><<<dim3(9, 32), 512, 0, stream>>>(xn, wqkv, qb, kb, vtb,
                                              BATCH * NSEQ, 1152, DIMC, qscale);

  // barrier-free attention: 512 blocks x 4 independent waves
  attn_causal<<<512, 256, 0, stream>>>(qb, kb, vtb, ao);

  gemm_bt<0><<<dim3(8, 32), 512, 0, stream>>>(ao, wob, yb, nullptr, nullptr,
                                              BATCH * NSEQ, DIMC, DIMC, 1.f);

  ln_bf16_to_f32<<<BATCH * NSEQ, 256, 0, stream>>>(yb, lno_g, lno_b, out);
}